// Round 8
// baseline (102.128 us; speedup 1.0000x reference)
//
#include <hip/hip_runtime.h>

// DCN-v2 low-rank mixture, L=3 E=4 D=512 R=64 B=16384.
// gate = softmax over size-1 axis == 1  -> G unused.
// xl' = x0 * (sum_e U_e tanh(C_e tanh(V_e^T xl)) + 4*bias) + xl, rows independent.
// R8: = R7 (fp16 MFMA, xl carry in LDS, zero persistent reg state) with v/cv
//     merged into ONE shared 16KB LDS buffer (+1 barrier per layer) ->
//     LDS 48KB/block -> 3 blocks/CU -> 24 waves/CU (was 16).

#define NL 3
#define NE 4
#define DD 512
#define RR 64
#define ROWS 32    // rows per block; grid = 16384/32 = 512 blocks
#define THREADS 512

typedef __attribute__((ext_vector_type(8))) _Float16 f16x8;   // 8 fp16 = 4 VGPR
typedef __attribute__((ext_vector_type(4))) float f32x4;

#define MFMA(a, b, c) __builtin_amdgcn_mfma_f32_16x16x32_f16((a), (b), (c), 0, 0, 0)

__device__ __forceinline__ short f16b(float f) {
    _Float16 h = (_Float16)f;
    return __builtin_bit_cast(short, h);
}
__device__ __forceinline__ float f16tof(short s) {
    return (float)__builtin_bit_cast(_Float16, s);
}

__device__ __forceinline__ float ftanh(float x) {
    float t = __builtin_amdgcn_exp2f(x * 2.8853900817779268f);
    return 1.0f - 2.0f * __builtin_amdgcn_rcpf(t + 1.0f);
}

// ---- prep: fp16-cast + permute weights into MFMA-fragment-contiguous order ----
// Fragment element (lane ln, j): col = 16*colblk + (ln&15), k = 32*kstep + (ln>>4)*8 + j.
// Vb2[l][colblk(16)][ks(16)][ln(64)][j(8)]  = V[l][e=colblk>>2][d=32ks+8(ln>>4)+j][r=16(colblk&3)+(ln&15)]
// Ub2[l][dblk(32)][ks(8)][ln][j]            = U[l][e=ks>>1][d=16dblk+(ln&15)][s=32(ks&1)+8(ln>>4)+j]
// Ct2[l][e(4)][oc(4)][kc(2)][ln][j]         = C[l][e][r=32kc+8(ln>>4)+j][s=16oc+(ln&15)]
__global__ void prep_kernel(const float* __restrict__ U, const float* __restrict__ V,
                            const float* __restrict__ C,
                            short* __restrict__ Vb2, short* __restrict__ Ub2,
                            short* __restrict__ Ct2)
{
    int tid  = blockIdx.x * 256 + threadIdx.x;
    int nthr = gridDim.x * 256;
    for (int i = tid; i < NL * 131072; i += nthr) {
        int l = i >> 17; int q = i & 131071;
        int colblk = q >> 13; int rem = q & 8191;
        int ks = rem >> 9; int ln = (rem >> 3) & 63; int j = rem & 7;
        int e = colblk >> 2;
        int r = (colblk & 3) * 16 + (ln & 15);
        int d = ks * 32 + (ln >> 4) * 8 + j;
        Vb2[i] = f16b(V[(((size_t)l * NE + e) * DD + d) * RR + r]);
    }
    for (int i = tid; i < NL * 131072; i += nthr) {
        int l = i >> 17; int q = i & 131071;
        int dblk = q >> 12; int rem = q & 4095;
        int ks = rem >> 9; int ln = (rem >> 3) & 63; int j = rem & 7;
        int e = ks >> 1;
        int d = dblk * 16 + (ln & 15);
        int s = (ks & 1) * 32 + (ln >> 4) * 8 + j;
        Ub2[i] = f16b(U[(((size_t)l * NE + e) * DD + d) * RR + s]);
    }
    for (int i = tid; i < NL * 16384; i += nthr) {
        int l = i >> 14; int q = i & 16383;
        int e = q >> 12; int rem = q & 4095;
        int oc = rem >> 10; int kc = (rem >> 9) & 1;
        int ln = (rem >> 3) & 63; int j = rem & 7;
        int r = kc * 32 + (ln >> 4) * 8 + j;
        int s = oc * 16 + (ln & 15);
        Ct2[i] = f16b(C[(((size_t)l * NE + e) * RR + r) * RR + s]);
    }
}

// XOR swizzle: breaks the 16-way bank conflict of row-major fp16 tiles on ds_read_b128
#define XLB_ADDR(row, colbyte) (((row) * (DD * 2)) + ((colbyte) ^ (((row) & 7) << 4)))
#define VB_ADDR(row, colbyte)  (((row) * (NE * RR * 2)) + ((colbyte) ^ (((row) & 7) << 4)))

__global__ __launch_bounds__(THREADS, 4) void dcn_main(
    const float* __restrict__ x,
    const float* __restrict__ bias,
    const short* __restrict__ Vb2,
    const short* __restrict__ Ub2,
    const short* __restrict__ Ct2,
    float* __restrict__ out)
{
    __shared__ char xl_b[ROWS * DD * 2];        // 32 KiB fp16 xl carry tile (swizzled)
    __shared__ char sbuf[ROWS * NE * RR * 2];   // 16 KiB shared v/cv tile (swizzled)

    const int t   = threadIdx.x;
    const int w   = t >> 6;          // wave 0..7
    const int ln  = t & 63;
    const int l15 = ln & 15;
    const int kg  = ln >> 4;         // k-group 0..3
    const int row_base = blockIdx.x * ROWS;

    // ---- preamble: x (fp32) -> fp16 LDS tile; no per-thread state kept ----
    #pragma unroll
    for (int q = 0; q < 8; ++q) {
        int p   = t + q * THREADS;
        int row = p >> 7;                 // 128 float4 per row
        int d4  = (p & 127) << 2;
        const float4 v4 = *(const float4*)(x + (size_t)(row_base + row) * DD + d4);
        short4 pk;
        pk.x = f16b(v4.x); pk.y = f16b(v4.y); pk.z = f16b(v4.z); pk.w = f16b(v4.w);
        *(short4*)(xl_b + XLB_ADDR(row, d4 * 2)) = pk;
    }
    __syncthreads();

    const int e2 = w >> 1;           // GEMM2 expert for this wave
    const int h2 = w & 1;            // GEMM2 column-half within expert

    #pragma unroll
    for (int layer = 0; layer < NL; ++layer) {
        const short* Vl = Vb2 + layer * 131072;
        const short* Ul = Ub2 + layer * 131072;
        const short* Cl = Ct2 + layer * 16384;
        const float* bl = bias + layer * DD;

        // ---- GEMM1: v = tanh(xl @ V); wave owns v-cols [w*32, w*32+32) ----
        f32x4 acc1[2][2];
        #pragma unroll
        for (int mt = 0; mt < 2; ++mt)
          #pragma unroll
          for (int nt = 0; nt < 2; ++nt) { f32x4 z = {0.f, 0.f, 0.f, 0.f}; acc1[mt][nt] = z; }

        #pragma unroll 4
        for (int ks = 0; ks < 16; ++ks) {
            const int d0 = ks * 32 + kg * 8;
            f16x8 a0 = *(const f16x8*)(xl_b + XLB_ADDR(l15,      d0 * 2));
            f16x8 a1 = *(const f16x8*)(xl_b + XLB_ADDR(l15 + 16, d0 * 2));
            #pragma unroll
            for (int nt = 0; nt < 2; ++nt) {
                f16x8 b = *(const f16x8*)(Vl + (((w * 2 + nt) * 16 + ks) << 9) + ln * 8);
                acc1[0][nt] = MFMA(a0, b, acc1[0][nt]);
                acc1[1][nt] = MFMA(a1, b, acc1[1][nt]);
            }
        }
        #pragma unroll
        for (int mt = 0; mt < 2; ++mt)
          #pragma unroll
          for (int nt = 0; nt < 2; ++nt)
            #pragma unroll
            for (int r = 0; r < 4; ++r) {
                int row = mt * 16 + kg * 4 + r;
                int col = w * 32 + nt * 16 + l15;
                *(short*)(sbuf + VB_ADDR(row, col * 2)) = f16b(ftanh(acc1[mt][nt][r]));
            }
        __syncthreads();

        // ---- GEMM2: cv = tanh(v @ C_e); wave pair (2e,2e+1) owns expert e ----
        f32x4 acc2[2][2];
        #pragma unroll
        for (int mt = 0; mt < 2; ++mt)
          #pragma unroll
          for (int nt = 0; nt < 2; ++nt) { f32x4 z = {0.f, 0.f, 0.f, 0.f}; acc2[mt][nt] = z; }

        #pragma unroll
        for (int kc = 0; kc < 2; ++kc) {
            const int r0 = kc * 32 + kg * 8;
            const int vcol = e2 * 64 + r0;
            f16x8 a0 = *(const f16x8*)(sbuf + VB_ADDR(l15,      vcol * 2));
            f16x8 a1 = *(const f16x8*)(sbuf + VB_ADDR(l15 + 16, vcol * 2));
            #pragma unroll
            for (int nt = 0; nt < 2; ++nt) {
                f16x8 b = *(const f16x8*)(Cl + (((e2 * 4 + h2 * 2 + nt) * 2 + kc) << 9) + ln * 8);
                acc2[0][nt] = MFMA(a0, b, acc2[0][nt]);
                acc2[1][nt] = MFMA(a1, b, acc2[1][nt]);
            }
        }
        // finish tanh in regs; all waves' v-reads must complete before cv overwrites sbuf
        float cvv[2][2][4];
        #pragma unroll
        for (int mt = 0; mt < 2; ++mt)
          #pragma unroll
          for (int nt = 0; nt < 2; ++nt)
            #pragma unroll
            for (int r = 0; r < 4; ++r) cvv[mt][nt][r] = ftanh(acc2[mt][nt][r]);
        __syncthreads();
        #pragma unroll
        for (int mt = 0; mt < 2; ++mt)
          #pragma unroll
          for (int nt = 0; nt < 2; ++nt)
            #pragma unroll
            for (int r = 0; r < 4; ++r) {
                int row = mt * 16 + kg * 4 + r;
                int col = e2 * 64 + h2 * 32 + nt * 16 + l15;
                *(short*)(sbuf + VB_ADDR(row, col * 2)) = f16b(cvv[mt][nt][r]);
            }
        __syncthreads();

        // ---- GEMM3: ucv = cv @ W, W[(e,s)][d] = U[e][d][s]; wave owns d-cols [w*64, +64) ----
        f32x4 acc3[2][4];
        #pragma unroll
        for (int mt = 0; mt < 2; ++mt)
          #pragma unroll
          for (int nt = 0; nt < 4; ++nt) { f32x4 z = {0.f, 0.f, 0.f, 0.f}; acc3[mt][nt] = z; }

        #pragma unroll 2
        for (int ks = 0; ks < 8; ++ks) {
            const int k0 = ks * 32 + kg * 8;
            f16x8 a0 = *(const f16x8*)(sbuf + VB_ADDR(l15,      k0 * 2));
            f16x8 a1 = *(const f16x8*)(sbuf + VB_ADDR(l15 + 16, k0 * 2));
            #pragma unroll
            for (int nt = 0; nt < 4; ++nt) {
                f16x8 b = *(const f16x8*)(Ul + (((w * 4 + nt) * 8 + ks) << 9) + ln * 8);
                acc3[0][nt] = MFMA(a0, b, acc3[0][nt]);
                acc3[1][nt] = MFMA(a1, b, acc3[1][nt]);
            }
        }

        // ---- epilogue: xl' = x0*(ucv + 4*bias) + xl_old; carry stays in LDS fp16 ----
        // layer 0: x0 == xl_old (LDS). layers 1,2: x0 re-read from global x (L2-resident).
        const bool lastL = (layer == NL - 1);
        #pragma unroll
        for (int nt = 0; nt < 4; ++nt) {
            const int col = w * 64 + nt * 16 + l15;
            const float bv = 4.0f * bl[col];
            #pragma unroll
            for (int mt = 0; mt < 2; ++mt) {
                const int row0 = mt * 16 + kg * 4;
                // xl_old from LDS fp16
                float xo0 = f16tof(*(const short*)(xl_b + XLB_ADDR(row0 + 0, col * 2)));
                float xo1 = f16tof(*(const short*)(xl_b + XLB_ADDR(row0 + 1, col * 2)));
                float xo2 = f16tof(*(const short*)(xl_b + XLB_ADDR(row0 + 2, col * 2)));
                float xo3 = f16tof(*(const short*)(xl_b + XLB_ADDR(row0 + 3, col * 2)));
                float x00, x01, x02, x03;
                if (layer == 0) {
                    x00 = xo0; x01 = xo1; x02 = xo2; x03 = xo3;
                } else {
                    const float* xp = x + (size_t)(row_base + row0) * DD + col;
                    x00 = xp[0]; x01 = xp[DD]; x02 = xp[2 * DD]; x03 = xp[3 * DD];
                }
                float n0 = x00 * (acc3[mt][nt][0] + bv) + xo0;
                float n1 = x01 * (acc3[mt][nt][1] + bv) + xo1;
                float n2 = x02 * (acc3[mt][nt][2] + bv) + xo2;
                float n3 = x03 * (acc3[mt][nt][3] + bv) + xo3;
                if (lastL) {
                    float* op = out + (size_t)(row_base + row0) * DD + col;
                    op[0] = n0; op[DD] = n1; op[2 * DD] = n2; op[3 * DD] = n3;
                } else {
                    *(short*)(xl_b + XLB_ADDR(row0 + 0, col * 2)) = f16b(n0);
                    *(short*)(xl_b + XLB_ADDR(row0 + 1, col * 2)) = f16b(n1);
                    *(short*)(xl_b + XLB_ADDR(row0 + 2, col * 2)) = f16b(n2);
                    *(short*)(xl_b + XLB_ADDR(row0 + 3, col * 2)) = f16b(n3);
                }
            }
        }
        if (!lastL) __syncthreads();   // next GEMM1 reads all xl cols; also guards sbuf reuse
    }
}

extern "C" void kernel_launch(void* const* d_in, const int* in_sizes, int n_in,
                              void* d_out, int out_size, void* d_ws, size_t ws_size,
                              hipStream_t stream) {
    const float* x    = (const float*)d_in[0];
    const float* U    = (const float*)d_in[1];
    const float* V    = (const float*)d_in[2];
    const float* C    = (const float*)d_in[3];
    // d_in[4] = G : unused (gate == 1 exactly)
    const float* bias = (const float*)d_in[5];
    float* out = (float*)d_out;

    short* Vb2 = (short*)d_ws;                 // 786432 B
    short* Ub2 = Vb2 + NL * 131072;            // 786432 B
    short* Ct2 = Ub2 + NL * 131072;            // 98304 B  (total ~1.6 MiB)

    prep_kernel<<<dim3(256), dim3(256), 0, stream>>>(U, V, C, Vb2, Ub2, Ct2);
    dcn_main<<<dim3(16384 / ROWS), dim3(THREADS), 0, stream>>>(x, bias, Vb2, Ub2, Ct2, out);
}

// Round 9
// 87.723 us; speedup vs baseline: 1.1642x; 1.1642x over previous
//
#include <hip/hip_runtime.h>

// DCN-v2 low-rank mixture, L=3 E=4 D=512 R=64 B=16384.
// gate = softmax over size-1 axis == 1  -> G unused.
// xl' = x0 * (sum_e U_e tanh(C_e tanh(V_e^T xl)) + 4*bias) + xl, rows independent.
// R9: = R8 with (1) x0 kept as fp16 in LDS (kills 67MB HBM re-read + epilogue
//     global latency; uniform code, no layer-0 branch), (2) final output staged
//     through LDS -> fully coalesced float4 stores (kills ~2x write amplification),
//     (3) waves_per_eu(4,4) on scratch-free code + deeper k-unroll for more
//     weight loads in flight. Grid 512 (2 blocks/CU), LDS 80KB.

#define NL 3
#define NE 4
#define DD 512
#define RR 64
#define ROWS 32    // rows per block; grid = 16384/32 = 512 blocks
#define THREADS 512

typedef __attribute__((ext_vector_type(8))) _Float16 f16x8;   // 8 fp16 = 4 VGPR
typedef __attribute__((ext_vector_type(4))) float f32x4;

#define MFMA(a, b, c) __builtin_amdgcn_mfma_f32_16x16x32_f16((a), (b), (c), 0, 0, 0)

__device__ __forceinline__ short f16b(float f) {
    _Float16 h = (_Float16)f;
    return __builtin_bit_cast(short, h);
}
__device__ __forceinline__ float f16tof(short s) {
    return (float)__builtin_bit_cast(_Float16, s);
}

__device__ __forceinline__ float ftanh(float x) {
    float t = __builtin_amdgcn_exp2f(x * 2.8853900817779268f);
    return 1.0f - 2.0f * __builtin_amdgcn_rcpf(t + 1.0f);
}

// ---- prep: fp16-cast + permute weights into MFMA-fragment-contiguous order ----
// Fragment element (lane ln, j): col = 16*colblk + (ln&15), k = 32*kstep + (ln>>4)*8 + j.
// Vb2[l][colblk(16)][ks(16)][ln(64)][j(8)]  = V[l][e=colblk>>2][d=32ks+8(ln>>4)+j][r=16(colblk&3)+(ln&15)]
// Ub2[l][dblk(32)][ks(8)][ln][j]            = U[l][e=ks>>1][d=16dblk+(ln&15)][s=32(ks&1)+8(ln>>4)+j]
// Ct2[l][e(4)][oc(4)][kc(2)][ln][j]         = C[l][e][r=32kc+8(ln>>4)+j][s=16oc+(ln&15)]
__global__ void prep_kernel(const float* __restrict__ U, const float* __restrict__ V,
                            const float* __restrict__ C,
                            short* __restrict__ Vb2, short* __restrict__ Ub2,
                            short* __restrict__ Ct2)
{
    int tid  = blockIdx.x * 256 + threadIdx.x;
    int nthr = gridDim.x * 256;
    for (int i = tid; i < NL * 131072; i += nthr) {
        int l = i >> 17; int q = i & 131071;
        int colblk = q >> 13; int rem = q & 8191;
        int ks = rem >> 9; int ln = (rem >> 3) & 63; int j = rem & 7;
        int e = colblk >> 2;
        int r = (colblk & 3) * 16 + (ln & 15);
        int d = ks * 32 + (ln >> 4) * 8 + j;
        Vb2[i] = f16b(V[(((size_t)l * NE + e) * DD + d) * RR + r]);
    }
    for (int i = tid; i < NL * 131072; i += nthr) {
        int l = i >> 17; int q = i & 131071;
        int dblk = q >> 12; int rem = q & 4095;
        int ks = rem >> 9; int ln = (rem >> 3) & 63; int j = rem & 7;
        int e = ks >> 1;
        int d = dblk * 16 + (ln & 15);
        int s = (ks & 1) * 32 + (ln >> 4) * 8 + j;
        Ub2[i] = f16b(U[(((size_t)l * NE + e) * DD + d) * RR + s]);
    }
    for (int i = tid; i < NL * 16384; i += nthr) {
        int l = i >> 14; int q = i & 16383;
        int e = q >> 12; int rem = q & 4095;
        int oc = rem >> 10; int kc = (rem >> 9) & 1;
        int ln = (rem >> 3) & 63; int j = rem & 7;
        int r = kc * 32 + (ln >> 4) * 8 + j;
        int s = oc * 16 + (ln & 15);
        Ct2[i] = f16b(C[(((size_t)l * NE + e) * RR + r) * RR + s]);
    }
}

// XOR swizzle: breaks the 16-way bank conflict of row-major fp16 tiles on ds_read_b128
#define XLB_ADDR(row, colbyte) (((row) * (DD * 2)) + ((colbyte) ^ (((row) & 7) << 4)))
#define VB_ADDR(row, colbyte)  (((row) * (NE * RR * 2)) + ((colbyte) ^ (((row) & 7) << 4)))

__global__ __launch_bounds__(THREADS)
__attribute__((amdgpu_waves_per_eu(4, 4)))
void dcn_main(
    const float* __restrict__ x,
    const float* __restrict__ bias,
    const short* __restrict__ Vb2,
    const short* __restrict__ Ub2,
    const short* __restrict__ Ct2,
    float* __restrict__ out)
{
    __shared__ char xl_b[ROWS * DD * 2];        // 32 KiB fp16 xl carry tile (swizzled)
    __shared__ char x0_b[ROWS * DD * 2];        // 32 KiB fp16 x0 tile (swizzled)
    __shared__ char sbuf[ROWS * NE * RR * 2];   // 16 KiB shared v/cv tile (swizzled)

    const int t   = threadIdx.x;
    const int w   = t >> 6;          // wave 0..7
    const int ln  = t & 63;
    const int l15 = ln & 15;
    const int kg  = ln >> 4;         // k-group 0..3
    const int row_base = blockIdx.x * ROWS;

    // ---- preamble: x (fp32, coalesced float4) -> fp16 xl_b AND x0_b ----
    #pragma unroll
    for (int q = 0; q < 8; ++q) {
        int p   = t + q * THREADS;
        int row = p >> 7;                 // 128 float4 per row
        int d4  = (p & 127) << 2;
        const float4 v4 = *(const float4*)(x + (size_t)(row_base + row) * DD + d4);
        short4 pk;
        pk.x = f16b(v4.x); pk.y = f16b(v4.y); pk.z = f16b(v4.z); pk.w = f16b(v4.w);
        *(short4*)(xl_b + XLB_ADDR(row, d4 * 2)) = pk;
        *(short4*)(x0_b + XLB_ADDR(row, d4 * 2)) = pk;
    }
    __syncthreads();

    const int e2 = w >> 1;           // GEMM2 expert for this wave
    const int h2 = w & 1;            // GEMM2 column-half within expert

    #pragma unroll
    for (int layer = 0; layer < NL; ++layer) {
        const short* Vl = Vb2 + layer * 131072;
        const short* Ul = Ub2 + layer * 131072;
        const short* Cl = Ct2 + layer * 16384;
        const float* bl = bias + layer * DD;

        // ---- GEMM1: v = tanh(xl @ V); wave owns v-cols [w*32, w*32+32) ----
        f32x4 acc1[2][2];
        #pragma unroll
        for (int mt = 0; mt < 2; ++mt)
          #pragma unroll
          for (int nt = 0; nt < 2; ++nt) { f32x4 z = {0.f, 0.f, 0.f, 0.f}; acc1[mt][nt] = z; }

        #pragma unroll 8
        for (int ks = 0; ks < 16; ++ks) {
            const int d0 = ks * 32 + kg * 8;
            f16x8 a0 = *(const f16x8*)(xl_b + XLB_ADDR(l15,      d0 * 2));
            f16x8 a1 = *(const f16x8*)(xl_b + XLB_ADDR(l15 + 16, d0 * 2));
            #pragma unroll
            for (int nt = 0; nt < 2; ++nt) {
                f16x8 b = *(const f16x8*)(Vl + (((w * 2 + nt) * 16 + ks) << 9) + ln * 8);
                acc1[0][nt] = MFMA(a0, b, acc1[0][nt]);
                acc1[1][nt] = MFMA(a1, b, acc1[1][nt]);
            }
        }
        #pragma unroll
        for (int mt = 0; mt < 2; ++mt)
          #pragma unroll
          for (int nt = 0; nt < 2; ++nt)
            #pragma unroll
            for (int r = 0; r < 4; ++r) {
                int row = mt * 16 + kg * 4 + r;
                int col = w * 32 + nt * 16 + l15;
                *(short*)(sbuf + VB_ADDR(row, col * 2)) = f16b(ftanh(acc1[mt][nt][r]));
            }
        __syncthreads();

        // ---- GEMM2: cv = tanh(v @ C_e); wave pair (2e,2e+1) owns expert e ----
        f32x4 acc2[2][2];
        #pragma unroll
        for (int mt = 0; mt < 2; ++mt)
          #pragma unroll
          for (int nt = 0; nt < 2; ++nt) { f32x4 z = {0.f, 0.f, 0.f, 0.f}; acc2[mt][nt] = z; }

        #pragma unroll
        for (int kc = 0; kc < 2; ++kc) {
            const int r0 = kc * 32 + kg * 8;
            const int vcol = e2 * 64 + r0;
            f16x8 a0 = *(const f16x8*)(sbuf + VB_ADDR(l15,      vcol * 2));
            f16x8 a1 = *(const f16x8*)(sbuf + VB_ADDR(l15 + 16, vcol * 2));
            #pragma unroll
            for (int nt = 0; nt < 2; ++nt) {
                f16x8 b = *(const f16x8*)(Cl + (((e2 * 4 + h2 * 2 + nt) * 2 + kc) << 9) + ln * 8);
                acc2[0][nt] = MFMA(a0, b, acc2[0][nt]);
                acc2[1][nt] = MFMA(a1, b, acc2[1][nt]);
            }
        }
        // finish tanh in regs; all waves' v-reads must complete before cv overwrites sbuf
        float cvv[2][2][4];
        #pragma unroll
        for (int mt = 0; mt < 2; ++mt)
          #pragma unroll
          for (int nt = 0; nt < 2; ++nt)
            #pragma unroll
            for (int r = 0; r < 4; ++r) cvv[mt][nt][r] = ftanh(acc2[mt][nt][r]);
        __syncthreads();
        #pragma unroll
        for (int mt = 0; mt < 2; ++mt)
          #pragma unroll
          for (int nt = 0; nt < 2; ++nt)
            #pragma unroll
            for (int r = 0; r < 4; ++r) {
                int row = mt * 16 + kg * 4 + r;
                int col = e2 * 64 + h2 * 32 + nt * 16 + l15;
                *(short*)(sbuf + VB_ADDR(row, col * 2)) = f16b(cvv[mt][nt][r]);
            }
        __syncthreads();

        // ---- GEMM3: ucv = cv @ W, W[(e,s)][d] = U[e][d][s]; wave owns d-cols [w*64, +64) ----
        f32x4 acc3[2][4];
        #pragma unroll
        for (int mt = 0; mt < 2; ++mt)
          #pragma unroll
          for (int nt = 0; nt < 4; ++nt) { f32x4 z = {0.f, 0.f, 0.f, 0.f}; acc3[mt][nt] = z; }

        #pragma unroll 4
        for (int ks = 0; ks < 8; ++ks) {
            const int k0 = ks * 32 + kg * 8;
            f16x8 a0 = *(const f16x8*)(sbuf + VB_ADDR(l15,      k0 * 2));
            f16x8 a1 = *(const f16x8*)(sbuf + VB_ADDR(l15 + 16, k0 * 2));
            #pragma unroll
            for (int nt = 0; nt < 4; ++nt) {
                f16x8 b = *(const f16x8*)(Ul + (((w * 4 + nt) * 8 + ks) << 9) + ln * 8);
                acc3[0][nt] = MFMA(a0, b, acc3[0][nt]);
                acc3[1][nt] = MFMA(a1, b, acc3[1][nt]);
            }
        }

        // ---- epilogue (pure LDS): xl' = x0*(ucv + 4*bias) + xl_old ----
        #pragma unroll
        for (int nt = 0; nt < 4; ++nt) {
            const int col = w * 64 + nt * 16 + l15;
            const float bv = 4.0f * bl[col];
            #pragma unroll
            for (int mt = 0; mt < 2; ++mt) {
                const int row0 = mt * 16 + kg * 4;
                #pragma unroll
                for (int r = 0; r < 4; ++r) {
                    float xo = f16tof(*(const short*)(xl_b + XLB_ADDR(row0 + r, col * 2)));
                    float x0 = f16tof(*(const short*)(x0_b + XLB_ADDR(row0 + r, col * 2)));
                    float n  = x0 * (acc3[mt][nt][r] + bv) + xo;
                    *(short*)(xl_b + XLB_ADDR(row0 + r, col * 2)) = f16b(n);
                }
            }
        }
        __syncthreads();   // next GEMM1 reads all xl cols / final copy reads all
    }

    // ---- final: coalesced float4 store of xl_b (fp16 -> fp32) ----
    #pragma unroll
    for (int q = 0; q < 8; ++q) {
        int p   = t + q * THREADS;
        int row = p >> 7;
        int d4  = (p & 127) << 2;
        short4 pk = *(const short4*)(xl_b + XLB_ADDR(row, d4 * 2));
        float4 v4;
        v4.x = f16tof(pk.x); v4.y = f16tof(pk.y); v4.z = f16tof(pk.z); v4.w = f16tof(pk.w);
        *(float4*)(out + (size_t)(row_base + row) * DD + d4) = v4;
    }
}

extern "C" void kernel_launch(void* const* d_in, const int* in_sizes, int n_in,
                              void* d_out, int out_size, void* d_ws, size_t ws_size,
                              hipStream_t stream) {
    const float* x    = (const float*)d_in[0];
    const float* U    = (const float*)d_in[1];
    const float* V    = (const float*)d_in[2];
    const float* C    = (const float*)d_in[3];
    // d_in[4] = G : unused (gate == 1 exactly)
    const float* bias = (const float*)d_in[5];
    float* out = (float*)d_out;

    short* Vb2 = (short*)d_ws;                 // 786432 B
    short* Ub2 = Vb2 + NL * 131072;            // 786432 B
    short* Ct2 = Ub2 + NL * 131072;            // 98304 B  (total ~1.6 MiB)

    prep_kernel<<<dim3(256), dim3(256), 0, stream>>>(U, V, C, Vb2, Ub2, Ct2);
    dcn_main<<<dim3(16384 / ROWS), dim3(THREADS), 0, stream>>>(x, bias, Vb2, Ub2, Ct2, out);
}